// Round 8
// baseline (179.766 us; speedup 1.0000x reference)
//
#include <hip/hip_runtime.h>
#include <hip/hip_bf16.h>

#define B_  4
#define C_  256
#define C2_ 128
#define N_  4096
#define LOG2E 1.4426950408889634f

typedef unsigned short u16;
typedef __attribute__((ext_vector_type(8))) short bf16x8;  // 8 bf16 in 4 VGPRs
typedef __attribute__((ext_vector_type(4))) float f32x4;

static __device__ __forceinline__ u16 f2bf(float f) {
    return __builtin_bit_cast(u16, __float2bfloat16(f));
}
static __device__ __forceinline__ float bf2f(u16 u) {
    return __bfloat162float(__builtin_bit_cast(__hip_bfloat16, u));
}

// ---------------------------------------------------------------------------
// Kernel 0 (prepw): pack {w_theta,w_phi,w_g,w_out} fp32 -> bf16 into Wb.
// 4 mats x 32768 elements. 128 blocks x 256 thr x 4 elem.
// ---------------------------------------------------------------------------
__global__ __launch_bounds__(256) void prepw_kernel(
    const float* __restrict__ wt, const float* __restrict__ wp,
    const float* __restrict__ wg, const float* __restrict__ wo,
    u16* __restrict__ Wb) {
    int i = (blockIdx.x * 256 + threadIdx.x) * 4;   // [0, 131072)
    int mat = i >> 15, off = i & 32767;
    const float* src = mat == 0 ? wt : (mat == 1 ? wp : (mat == 2 ? wg : wo));
    float4 v = *(const float4*)(src + off);
    ushort4 o = { f2bf(v.x), f2bf(v.y), f2bf(v.z), f2bf(v.w) };
    *(ushort4*)(Wb + i) = o;
}

// ---------------------------------------------------------------------------
// Kernel 1 (projx): fused x-transpose + 3-way MFMA projection (no XT pass).
// One block per (b, 32-n tile): stage x[b][:,n0:n0+32] fp32 -> LDS bf16
// transposed, then theta/phi/g GEMMs sequentially with af[8] resident.
// Wave roles: mgrp=wave>>1 picks 16-row group, chalf=wave&1 picks c2 half.
// mat 0 -> Q (scaled log2e), mat 1 -> K, mat 2 -> V via Vt transpose bounce
// (Vt aliases XTs, dead after af load). grid = B*(N/32) = 512, 256 thr.
// ---------------------------------------------------------------------------
__global__ __launch_bounds__(256) void projx_kernel(
    const float* __restrict__ x, const u16* __restrict__ Wb,
    const float* __restrict__ b_theta, const float* __restrict__ b_phi,
    const float* __restrict__ b_g,
    u16* __restrict__ Q, u16* __restrict__ K, u16* __restrict__ V) {
    __shared__ __align__(16) union {
        u16 XTs[32][264];   // 16896 B  (transposed x tile, bf16)
        u16 Vt[128][40];    // 10240 B  (V transpose bounce)
    } sm;
    int bid = blockIdx.x;
    int b   = bid / (N_ / 32);
    int n0  = (bid % (N_ / 32)) * 32;
    int tid = threadIdx.x;
    int wave = tid >> 6, lane = tid & 63, quad = lane >> 4, l16 = lane & 15;
    int mgrp = wave >> 1, chalf = wave & 1;

    // ---- stage + transpose: 128 c-pairs x 8 n-quads = 1024 items ----
#pragma unroll
    for (int it = 0; it < 4; ++it) {
        int idx = it * 256 + tid;
        int q = idx & 7, p = idx >> 3;
        const float* r0 = x + ((size_t)b * C_ + 2 * p) * N_ + n0 + 4 * q;
        float4 v0 = *(const float4*)r0;
        float4 v1 = *(const float4*)(r0 + N_);
        const float* f0 = (const float*)&v0;
        const float* f1 = (const float*)&v1;
#pragma unroll
        for (int j = 0; j < 4; ++j) {
            unsigned pk = (unsigned)f2bf(f0[j]) | ((unsigned)f2bf(f1[j]) << 16);
            *(unsigned*)&sm.XTs[4 * q + j][2 * p] = pk;
        }
    }
    __syncthreads();

    // A fragments: A[m = n-local = mgrp*16+l16][k = ks*32+quad*8+j]
    bf16x8 af[8];
#pragma unroll
    for (int ks = 0; ks < 8; ++ks)
        af[ks] = *(const bf16x8*)&sm.XTs[mgrp * 16 + l16][ks * 32 + quad * 8];
    __syncthreads();   // XTs fully consumed -> Vt may alias

    const float* biases[3] = { b_theta, b_phi, b_g };
#pragma unroll
    for (int mat = 0; mat < 3; ++mat) {
        const u16* wm = Wb + (size_t)mat * C2_ * C_;
        const float* bias = biases[mat];
        f32x4 acc[4];
#pragma unroll
        for (int i = 0; i < 4; ++i) acc[i] = (f32x4){0.f, 0.f, 0.f, 0.f};
#pragma unroll
        for (int ct = 0; ct < 4; ++ct) {
            int ce = chalf * 4 + ct;
            const u16* wr = wm + (size_t)(ce * 16 + l16) * C_ + quad * 8;
#pragma unroll
            for (int ks = 0; ks < 8; ++ks) {
                bf16x8 bf = *(const bf16x8*)(wr + ks * 32);
                acc[ct] = __builtin_amdgcn_mfma_f32_16x16x32_bf16(af[ks], bf, acc[ct], 0, 0, 0);
            }
        }
        if (mat < 2) {
            u16* dst = mat == 0 ? Q : K;
            float sc = mat == 0 ? LOG2E : 1.0f;
#pragma unroll
            for (int ct = 0; ct < 4; ++ct) {
                int c2 = (chalf * 4 + ct) * 16 + l16;
                float bb = bias[c2];
#pragma unroll
                for (int r = 0; r < 4; ++r) {
                    int n = n0 + mgrp * 16 + quad * 4 + r;
                    dst[((size_t)b * N_ + n) * C2_ + c2] = f2bf((acc[ct][r] + bb) * sc);
                }
            }
        } else {
#pragma unroll
            for (int ct = 0; ct < 4; ++ct) {
                int c2 = (chalf * 4 + ct) * 16 + l16;
                float bb = bias[c2];
#pragma unroll
                for (int r = 0; r < 4; ++r)
                    sm.Vt[c2][mgrp * 16 + quad * 4 + r] = f2bf(acc[ct][r] + bb);
            }
        }
    }
    __syncthreads();
    // cooperative V[b][c2][n] write: 128 rows x 32 n bf16
    {
        int row = tid >> 1, col16 = (tid & 1) * 16;
        uint4 a0 = *(const uint4*)&sm.Vt[row][col16];
        uint4 a1 = *(const uint4*)&sm.Vt[row][col16 + 8];
        u16* vp = V + ((size_t)b * C2_ + row) * N_ + n0 + col16;
        *(uint4*)vp = a0;
        *(uint4*)(vp + 8) = a1;
    }
}

// ---------------------------------------------------------------------------
// Kernel 2: flash attention — round-5-proven body; split-K now supports
// UNEVEN splits (S=6 -> 11/11/11/11/10/10 tiles -> grid 768 = 3 blocks/CU,
// LDS 54272*3 = 162816 <= 163840). Op partials now bf16.
// ---------------------------------------------------------------------------
__global__ __launch_bounds__(256, 2) void attn_kernel(
    const u16* __restrict__ Q, const u16* __restrict__ K,
    const u16* __restrict__ V, u16* __restrict__ AO,
    u16* __restrict__ Opb, float* __restrict__ lsum, int nsplit) {
    const int BM = 128, BN = 64, D = C2_;
    const int per = B_ * (N_ / BM);      // 128
    int s    = blockIdx.x / per;
    int r0   = blockIdx.x % per;
    int b    = r0 / (N_ / BM);
    int m0   = (r0 % (N_ / BM)) * BM;
    int tid  = threadIdx.x;
    int wave = tid >> 6, lane = tid & 63, quad = (lane >> 4) & 3, l16 = lane & 15;

    __shared__ __align__(16) u16 Ks[BN][D + 8];        // 17408 B
    __shared__ __align__(16) u16 Vs[D][BN + 8];        // 18432 B
    __shared__ __align__(16) u16 Psb[4][32][BN + 8];   // 18432 B
    u16* Ps = &Psb[wave][0][0];

    bf16x8 qf[2][4];
#pragma unroll
    for (int ms = 0; ms < 2; ++ms) {
        const u16* qp = Q + ((size_t)b * N_ + m0 + wave * 32 + ms * 16 + l16) * D;
#pragma unroll
        for (int kk = 0; kk < 4; ++kk)
            qf[ms][kk] = *(const bf16x8*)(qp + kk * 32 + quad * 8);
    }

    float l_r[2][4] = {{0.f, 0.f, 0.f, 0.f}, {0.f, 0.f, 0.f, 0.f}};
    f32x4 o_acc[2][8];
#pragma unroll
    for (int ms = 0; ms < 2; ++ms)
#pragma unroll
        for (int i = 0; i < 8; ++i) o_acc[ms][i] = (f32x4){0.f, 0.f, 0.f, 0.f};

    // uneven tile split: tiles of 64 keys; split s gets base + (s<rem)
    const int tiles = N_ / BN;                 // 64
    const int base = tiles / nsplit, rem = tiles % nsplit;
    const int t0 = s * base + (s < rem ? s : rem);
    const int cnt = base + (s < rem ? 1 : 0);
    const int nt0 = t0 * BN, nt1 = (t0 + cnt) * BN;

    for (int nt = nt0; nt < nt1; nt += BN) {
        const u16* kp = K + ((size_t)b * N_ + nt) * D;
#pragma unroll
        for (int it = 0; it < 4; ++it) {
            int idx = it * 256 + tid;
            int row = idx >> 4, col = (idx & 15) * 8;
            *(uint4*)&Ks[row][col] = *(const uint4*)(kp + row * D + col);
        }
#pragma unroll
        for (int it = 0; it < 4; ++it) {
            int idx = it * 256 + tid;
            int row = idx >> 3, col = (idx & 7) * 8;
            *(uint4*)&Vs[row][col] =
                *(const uint4*)(V + ((size_t)b * C2_ + row) * N_ + nt + col);
        }
        __syncthreads();

        f32x4 sc[2][4];
#pragma unroll
        for (int nn = 0; nn < 4; ++nn) {
            f32x4 a0 = (f32x4){0.f, 0.f, 0.f, 0.f};
            f32x4 a1 = (f32x4){0.f, 0.f, 0.f, 0.f};
#pragma unroll
            for (int kk = 0; kk < 4; ++kk) {
                bf16x8 kf = *(const bf16x8*)&Ks[nn * 16 + l16][kk * 32 + quad * 8];
                a0 = __builtin_amdgcn_mfma_f32_16x16x32_bf16(qf[0][kk], kf, a0, 0, 0, 0);
                a1 = __builtin_amdgcn_mfma_f32_16x16x32_bf16(qf[1][kk], kf, a1, 0, 0, 0);
            }
            sc[0][nn] = a0;
            sc[1][nn] = a1;
        }

#pragma unroll
        for (int ms = 0; ms < 2; ++ms)
#pragma unroll
            for (int nn = 0; nn < 4; ++nn)
#pragma unroll
                for (int r = 0; r < 4; ++r) {
                    float p = __builtin_amdgcn_exp2f(sc[ms][nn][r]);
                    l_r[ms][r] += p;
                    Ps[(ms * 16 + quad * 4 + r) * (BN + 8) + nn * 16 + l16] = f2bf(p);
                }

#pragma unroll
        for (int ks = 0; ks < 2; ++ks) {
            bf16x8 pf0 = *(const bf16x8*)&Ps[(l16) * (BN + 8) + ks * 32 + quad * 8];
            bf16x8 pf1 = *(const bf16x8*)&Ps[(16 + l16) * (BN + 8) + ks * 32 + quad * 8];
#pragma unroll
            for (int cs = 0; cs < 8; ++cs) {
                bf16x8 vf = *(const bf16x8*)&Vs[cs * 16 + l16][ks * 32 + quad * 8];
                o_acc[0][cs] = __builtin_amdgcn_mfma_f32_16x16x32_bf16(pf0, vf, o_acc[0][cs], 0, 0, 0);
                o_acc[1][cs] = __builtin_amdgcn_mfma_f32_16x16x32_bf16(pf1, vf, o_acc[1][cs], 0, 0, 0);
            }
        }
        __syncthreads();
    }

#pragma unroll
    for (int ms = 0; ms < 2; ++ms)
#pragma unroll
        for (int r = 0; r < 4; ++r) {
            l_r[ms][r] += __shfl_xor(l_r[ms][r], 1);
            l_r[ms][r] += __shfl_xor(l_r[ms][r], 2);
            l_r[ms][r] += __shfl_xor(l_r[ms][r], 4);
            l_r[ms][r] += __shfl_xor(l_r[ms][r], 8);
        }

    if (Opb) {
#pragma unroll
        for (int ms = 0; ms < 2; ++ms) {
#pragma unroll
            for (int cs = 0; cs < 8; ++cs)
#pragma unroll
                for (int r = 0; r < 4; ++r) {
                    size_t row = (size_t)s * (B_ * N_) + (size_t)b * N_ +
                                 m0 + wave * 32 + ms * 16 + quad * 4 + r;
                    Opb[row * C2_ + cs * 16 + l16] = f2bf(o_acc[ms][cs][r]);
                }
            if (l16 == 0)
#pragma unroll
                for (int r = 0; r < 4; ++r) {
                    size_t row = (size_t)s * (B_ * N_) + (size_t)b * N_ +
                                 m0 + wave * 32 + ms * 16 + quad * 4 + r;
                    lsum[row] = l_r[ms][r];
                }
        }
    } else {
#pragma unroll
        for (int ms = 0; ms < 2; ++ms)
#pragma unroll
            for (int cs = 0; cs < 8; ++cs)
#pragma unroll
                for (int r = 0; r < 4; ++r) {
                    float v = o_acc[ms][cs][r] / l_r[ms][r];
                    AO[((size_t)b * N_ + m0 + wave * 32 + ms * 16 + quad * 4 + r) * C2_ +
                       cs * 16 + l16] = f2bf(v);
                }
    }
}

// ---------------------------------------------------------------------------
// Kernel 3: outproj with fused split-K combine (Op now bf16).
// ---------------------------------------------------------------------------
__global__ __launch_bounds__(256) void outproj_kernel(
    const float* __restrict__ x, const u16* __restrict__ Opb,
    const float* __restrict__ lsum, const u16* __restrict__ AO,
    const u16* __restrict__ Wob, const float* __restrict__ b_out,
    float* __restrict__ y, int nsplit) {
    __shared__ __align__(16) u16 As[64][C2_ + 8];   // 17408 B
    __shared__ float Ls[64];
    int bid = blockIdx.x;
    int per_b = (C_ / 64) * (N_ / 64);   // 256
    int b   = bid / per_b;
    int rem = bid % per_b;
    int c0  = (rem / (N_ / 64)) * 64;
    int n0  = (rem % (N_ / 64)) * 64;
    int tid = threadIdx.x;
    int wave = tid >> 6, lane = tid & 63, quad = lane >> 4, l16 = lane & 15;

    if (nsplit > 1) {   // grid-uniform branch
        if (tid < 64) {
            float L = 0.f;
            for (int s = 0; s < nsplit; ++s)
                L += lsum[(size_t)s * (B_ * N_) + (size_t)b * N_ + n0 + tid];
            Ls[tid] = 1.f / L;
        }
        __syncthreads();
#pragma unroll
        for (int it = 0; it < 4; ++it) {
            int idx = it * 256 + tid;           // 64 rows x 16 8-chunks
            int n = idx >> 4, c8 = (idx & 15) * 8;
            float a[8] = {0.f, 0.f, 0.f, 0.f, 0.f, 0.f, 0.f, 0.f};
            for (int s = 0; s < nsplit; ++s) {
                const u16* op = Opb +
                    ((size_t)s * (B_ * N_) + (size_t)b * N_ + n0 + n) * C2_ + c8;
                uint4 raw = *(const uint4*)op;
                const u16* rp = (const u16*)&raw;
#pragma unroll
                for (int j = 0; j < 8; ++j) a[j] += bf2f(rp[j]);
            }
            float inv = Ls[n];
            u16 o[8];
#pragma unroll
            for (int j = 0; j < 8; ++j) o[j] = f2bf(a[j] * inv);
            *(uint4*)&As[n][c8] = *(const uint4*)o;
        }
    } else {
#pragma unroll
        for (int it = 0; it < 4; ++it) {
            int idx = it * 256 + tid;
            int n = idx >> 4, c8 = (idx & 15) * 8;
            *(uint4*)&As[n][c8] =
                *(const uint4*)(AO + ((size_t)b * N_ + n0 + n) * C2_ + c8);
        }
    }
    __syncthreads();

    int cw = c0 + wave * 16;
    bf16x8 af[4];
#pragma unroll
    for (int kk = 0; kk < 4; ++kk)
        af[kk] = *(const bf16x8*)&Wob[(size_t)(cw + l16) * C2_ + kk * 32 + quad * 8];

    f32x4 acc[4];
#pragma unroll
    for (int i = 0; i < 4; ++i) acc[i] = (f32x4){0.f, 0.f, 0.f, 0.f};

#pragma unroll
    for (int nn = 0; nn < 4; ++nn)
#pragma unroll
        for (int kk = 0; kk < 4; ++kk) {
            bf16x8 bf = *(const bf16x8*)&As[nn * 16 + l16][kk * 32 + quad * 8];
            acc[nn] = __builtin_amdgcn_mfma_f32_16x16x32_bf16(af[kk], bf, acc[nn], 0, 0, 0);
        }

    float bo[4];
#pragma unroll
    for (int r = 0; r < 4; ++r) bo[r] = b_out[cw + quad * 4 + r];

#pragma unroll
    for (int nn = 0; nn < 4; ++nn)
#pragma unroll
        for (int r = 0; r < 4; ++r) {
            int c = cw + quad * 4 + r;
            size_t off = ((size_t)b * C_ + c) * N_ + n0 + nn * 16 + l16;
            y[off] = x[off] + bo[r] + acc[nn][r];
        }
}

// ---------------------------------------------------------------------------
extern "C" void kernel_launch(void* const* d_in, const int* in_sizes, int n_in,
                              void* d_out, int out_size, void* d_ws, size_t ws_size,
                              hipStream_t stream) {
    const float* x       = (const float*)d_in[0];
    const float* w_theta = (const float*)d_in[1];
    const float* b_theta = (const float*)d_in[2];
    const float* w_phi   = (const float*)d_in[3];
    const float* b_phi   = (const float*)d_in[4];
    const float* w_g     = (const float*)d_in[5];
    const float* b_g     = (const float*)d_in[6];
    const float* w_out   = (const float*)d_in[7];
    const float* b_out   = (const float*)d_in[8];
    float* y = (float*)d_out;

    const size_t SZ = (size_t)B_ * N_ * C2_;        // 2Mi elements
    u16* Q  = (u16*)d_ws;
    u16* K  = Q + SZ;
    u16* V  = K + SZ;
    u16* AO = V + SZ;
    u16* Wb = AO + SZ;                               // 4 mats bf16 = 256 KiB
    u16* Wob = Wb + (size_t)3 * C2_ * C_;
    char* dyn = (char*)(Wb + (size_t)4 * C2_ * C_);
    size_t fixedB = (size_t)(dyn - (char*)d_ws);     // ~16.25 MiB

    size_t perS = SZ * 2 + (size_t)B_ * N_ * 4;      // Op bf16 + lsum per split

    int S;
    if      (ws_size >= fixedB + 6 * perS) S = 6;
    else if (ws_size >= fixedB + 4 * perS) S = 4;
    else if (ws_size >= fixedB + 2 * perS) S = 2;
    else                                   S = 1;

    u16*   Opb = nullptr;
    float* ls  = nullptr;
    if (S > 1) {
        Opb = (u16*)dyn;
        ls  = (float*)(Opb + (size_t)S * SZ);
    }

    prepw_kernel<<<128, 256, 0, stream>>>(w_theta, w_phi, w_g, w_out, Wb);
    projx_kernel<<<B_ * (N_ / 32), 256, 0, stream>>>(
        x, Wb, b_theta, b_phi, b_g, Q, K, V);
    attn_kernel<<<B_ * (N_ / 128) * S, 256, 0, stream>>>(Q, K, V, AO, Opb, ls, S);
    outproj_kernel<<<B_ * (C_ / 64) * (N_ / 64), 256, 0, stream>>>(
        x, Opb, ls, AO, Wob, b_out, y, S);
}